// Round 4
// baseline (363.379 us; speedup 1.0000x reference)
//
#include <hip/hip_runtime.h>
#include <hip/hip_bf16.h>

typedef __bf16 bf16;
typedef __bf16 bf16x4 __attribute__((ext_vector_type(4)));
typedef __bf16 bf16x8 __attribute__((ext_vector_type(8)));
typedef float f32x4 __attribute__((ext_vector_type(4)));

#define GLP(p) ((const __attribute__((address_space(1))) void*)(p))
#define LDSP(p) ((__attribute__((address_space(3))) void*)(p))

// ---------------- fp32 -> bf16 convert ----------------
__global__ __launch_bounds__(256) void cvt_kernel(const float* __restrict__ in,
                                                  bf16* __restrict__ out, int n4) {
  int i = blockIdx.x * 256 + threadIdx.x;
  if (i < n4) {
    float4 v = reinterpret_cast<const float4*>(in)[i];
    bf16x4 o = { (bf16)v.x, (bf16)v.y, (bf16)v.z, (bf16)v.w };
    reinterpret_cast<bf16x4*>(out)[i] = o;
  }
}

// ---------------- fused QKV GEMM ----------------
// C[4096,3072] = Xb[4096,1024] @ Wb[3072,1024]^T + bias
// Epilogue scatters: Q,K -> [BH][S][64] bf16 ; V -> [BH][64][S] bf16 (transposed)
__global__ __launch_bounds__(256) void qkv_gemm(
    const bf16* __restrict__ Xb, const bf16* __restrict__ Wb,
    const float* __restrict__ biasq, const float* __restrict__ biask,
    const float* __restrict__ biasv,
    bf16* __restrict__ Qb, bf16* __restrict__ Kb, bf16* __restrict__ Vt) {
  __shared__ __align__(16) bf16 As[128 * 32];
  __shared__ __align__(16) bf16 Bs[128 * 32];
  const int tid = threadIdx.x;
  const int w = tid >> 6, l = tid & 63;
  const int lg = l >> 4, lr = l & 15;
  const int wr = w >> 1, wc = w & 1;
  const int bm = blockIdx.y * 128, bn = blockIdx.x * 128;

  f32x4 acc[4][4] = {};

  #pragma unroll 1
  for (int k0 = 0; k0 < 1024; k0 += 32) {
    #pragma unroll
    for (int i = 0; i < 2; ++i) {
      int row = i * 64 + (tid >> 2);
      int c8 = (tid & 3) * 8;
      __builtin_amdgcn_global_load_lds(GLP(Xb + (bm + row) * 1024 + k0 + c8),
                                       LDSP((char*)As + (i * 256 + w * 64) * 16),
                                       16, 0, 0);
      __builtin_amdgcn_global_load_lds(GLP(Wb + (bn + row) * 1024 + k0 + c8),
                                       LDSP((char*)Bs + (i * 256 + w * 64) * 16),
                                       16, 0, 0);
    }
    __syncthreads();
    bf16x8 af[4], bfq[4];
    #pragma unroll
    for (int t = 0; t < 4; ++t) {
      af[t]  = *reinterpret_cast<const bf16x8*>(
                   reinterpret_cast<const char*>(As) + (wr * 64 + t * 16 + lr) * 64 + lg * 16);
      bfq[t] = *reinterpret_cast<const bf16x8*>(
                   reinterpret_cast<const char*>(Bs) + (wc * 64 + t * 16 + lr) * 64 + lg * 16);
    }
    #pragma unroll
    for (int mt = 0; mt < 4; ++mt)
      #pragma unroll
      for (int nt = 0; nt < 4; ++nt)
        acc[mt][nt] = __builtin_amdgcn_mfma_f32_16x16x32_bf16(af[mt], bfq[nt], acc[mt][nt], 0, 0, 0);
    __syncthreads();
  }

  // epilogue: block's n-range lies entirely in one of {Q,K,V} (1024 % 128 == 0)
  const int mtx = blockIdx.x >> 3;
  const float* bp = (mtx == 0) ? biasq : (mtx == 1) ? biask : biasv;
  #pragma unroll
  for (int nt = 0; nt < 4; ++nt) {
    int ng = bn + wc * 64 + nt * 16 + lr;
    int nj = ng & 1023;
    int hh = nj >> 6, d = nj & 63;
    float bias = bp[nj];
    #pragma unroll
    for (int mt = 0; mt < 4; ++mt) {
      int m0 = bm + wr * 64 + mt * 16 + lg * 4;
      int bb = m0 >> 11, s0 = m0 & 2047;
      if (mtx == 2) {
        bf16x4 pk;
        #pragma unroll
        for (int r = 0; r < 4; ++r) pk[r] = (bf16)(acc[mt][nt][r] + bias);
        *reinterpret_cast<bf16x4*>(Vt + (((bb * 16 + hh) * 64 + d) * 2048 + s0)) = pk;
      } else {
        bf16* dst = (mtx == 0) ? Qb : Kb;
        #pragma unroll
        for (int r = 0; r < 4; ++r)
          dst[((bb * 16 + hh) * 2048 + s0 + r) * 64 + d] = (bf16)(acc[mt][nt][r] + bias);
      }
    }
  }
}

// ---------------- flash attention ----------------
// Q,K: [BH][2048][64] bf16 ; Vt: [BH][64][2048] bf16 ; out fp32 [B][S][NH][64]
__global__ __launch_bounds__(256) void attn_kernel(
    const bf16* __restrict__ Qb, const bf16* __restrict__ Kb,
    const bf16* __restrict__ Vt, const float* __restrict__ mask,
    float* __restrict__ out) {
  __shared__ __align__(16) bf16 Pl[4][16 * 72];  // per-wave P tile, padded stride 72 halves
  const int tid = threadIdx.x;
  const int w = tid >> 6, l = tid & 63;
  const int lg = l >> 4, lr = l & 15;
  // XCD swizzle: all 32 q-tiles of one (b,h) land on the same XCD -> K/V L2-resident
  const int blk = blockIdx.x;
  const int xcd = blk & 7, i0 = blk >> 3;
  const int bh = xcd * 4 + (i0 >> 5), qt = i0 & 31;
  const int bb = bh >> 4, hh = bh & 15;
  const int q16 = qt * 64 + w * 16;

  const bf16* Qp = Qb + (bh * 2048 + q16) * 64;
  const bf16* Kp = Kb + bh * 2048 * 64;
  const bf16* Vp = Vt + bh * 64 * 2048;
  const float* mp = mask + bb * 2048;

  bf16x8 aq[2];
  #pragma unroll
  for (int kk = 0; kk < 2; ++kk)
    aq[kk] = *reinterpret_cast<const bf16x8*>(Qp + lr * 64 + kk * 32 + lg * 8);

  f32x4 acc[4] = {};
  float mrun[4], lrun[4];
  #pragma unroll
  for (int r = 0; r < 4; ++r) { mrun[r] = -3.0e38f; lrun[r] = 0.f; }

  const float SC = 0.125f * 1.44269504f;  // 1/sqrt(64) * log2(e)
  bf16* pw = &Pl[w][0];

  #pragma unroll 1
  for (int kv0 = 0; kv0 < 2048; kv0 += 64) {
    // QK^T: scores sa[t][r], q = q16 + lg*4 + r, k = kv0 + t*16 + lr
    f32x4 sa[4];
    #pragma unroll
    for (int t = 0; t < 4; ++t) {
      f32x4 z = {};
      #pragma unroll
      for (int kk = 0; kk < 2; ++kk) {
        bf16x8 bk8 = *reinterpret_cast<const bf16x8*>(
            Kp + (kv0 + t * 16 + lr) * 64 + kk * 32 + lg * 8);
        z = __builtin_amdgcn_mfma_f32_16x16x32_bf16(aq[kk], bk8, z, 0, 0, 0);
      }
      sa[t] = z;
    }
    // scale + additive mask bias (base-2 domain)
    #pragma unroll
    for (int t = 0; t < 4; ++t) {
      float kb = (1.0f - mp[kv0 + t * 16 + lr]) * (-10000.0f * 1.44269504f);
      #pragma unroll
      for (int r = 0; r < 4; ++r) sa[t][r] = sa[t][r] * SC + kb;
    }
    // online softmax: row max / rescale factor
    float fac[4], mnew[4];
    #pragma unroll
    for (int r = 0; r < 4; ++r) {
      float rm = fmaxf(fmaxf(sa[0][r], sa[1][r]), fmaxf(sa[2][r], sa[3][r]));
      rm = fmaxf(rm, __shfl_xor(rm, 1));
      rm = fmaxf(rm, __shfl_xor(rm, 2));
      rm = fmaxf(rm, __shfl_xor(rm, 4));
      rm = fmaxf(rm, __shfl_xor(rm, 8));
      float mn = fmaxf(mrun[r], rm);
      fac[r] = exp2f(mrun[r] - mn);
      mrun[r] = mn;
      mnew[r] = mn;
    }
    // p = 2^(s-m), row sums, update l
    #pragma unroll
    for (int r = 0; r < 4; ++r) {
      float rs = 0.f;
      #pragma unroll
      for (int t = 0; t < 4; ++t) {
        float p = exp2f(sa[t][r] - mnew[r]);
        sa[t][r] = p;
        rs += p;
      }
      rs += __shfl_xor(rs, 1);
      rs += __shfl_xor(rs, 2);
      rs += __shfl_xor(rs, 4);
      rs += __shfl_xor(rs, 8);
      lrun[r] = lrun[r] * fac[r] + rs;
    }
    // rescale ctx accumulator
    #pragma unroll
    for (int nt = 0; nt < 4; ++nt)
      #pragma unroll
      for (int r = 0; r < 4; ++r) acc[nt][r] *= fac[r];
    // P -> LDS (bf16), transpose to A-fragment layout
    #pragma unroll
    for (int t = 0; t < 4; ++t)
      #pragma unroll
      for (int r = 0; r < 4; ++r)
        pw[(lg * 4 + r) * 72 + t * 16 + lr] = (bf16)sa[t][r];
    asm volatile("" ::: "memory");  // keep ds_write before ds_read; DS pipe is in-order per wave
    // PV: ctx[q][d] += P[q][k] * V[k][d], V read transposed (contiguous k)
    #pragma unroll
    for (int ks = 0; ks < 2; ++ks) {
      bf16x8 pa = *reinterpret_cast<const bf16x8*>(
          reinterpret_cast<const char*>(pw) + lr * 144 + ks * 64 + lg * 16);
      #pragma unroll
      for (int nt = 0; nt < 4; ++nt) {
        bf16x8 bv8 = *reinterpret_cast<const bf16x8*>(
            Vp + (nt * 16 + lr) * 2048 + kv0 + ks * 32 + lg * 8);
        acc[nt] = __builtin_amdgcn_mfma_f32_16x16x32_bf16(pa, bv8, acc[nt], 0, 0, 0);
      }
    }
    asm volatile("" ::: "memory");
  }

  #pragma unroll
  for (int r = 0; r < 4; ++r) {
    float inv = 1.0f / lrun[r];
    int sq = q16 + lg * 4 + r;
    #pragma unroll
    for (int nt = 0; nt < 4; ++nt) {
      int d = nt * 16 + lr;
      out[((bb * 2048 + sq) * 16 + hh) * 64 + d] = acc[nt][r] * inv;
    }
  }
}

extern "C" void kernel_launch(void* const* d_in, const int* in_sizes, int n_in,
                              void* d_out, int out_size, void* d_ws, size_t ws_size,
                              hipStream_t stream) {
  const float* hs   = (const float*)d_in[0];
  const float* mask = (const float*)d_in[1];
  const float* Wq   = (const float*)d_in[2];
  const float* bq   = (const float*)d_in[3];
  const float* Wk   = (const float*)d_in[4];
  const float* bk   = (const float*)d_in[5];
  const float* Wv   = (const float*)d_in[6];
  const float* bv   = (const float*)d_in[7];
  float* out = (float*)d_out;

  // workspace layout (bf16 elems): Xb 4.19M | Wb 3.15M | Qb 4.19M | Kb 4.19M | Vt 4.19M
  if (ws_size < 39845888u) return;  // need ~40 MB
  bf16* Xb = (bf16*)d_ws;
  bf16* Wb = Xb + 4194304;
  bf16* Qb = Wb + 3145728;
  bf16* Kb = Qb + 4194304;
  bf16* Vt = Kb + 4194304;

  cvt_kernel<<<4096, 256, 0, stream>>>(hs, Xb, 1048576);
  cvt_kernel<<<1024, 256, 0, stream>>>(Wq, Wb, 262144);
  cvt_kernel<<<1024, 256, 0, stream>>>(Wk, Wb + 1048576, 262144);
  cvt_kernel<<<1024, 256, 0, stream>>>(Wv, Wb + 2097152, 262144);
  qkv_gemm<<<dim3(24, 32), 256, 0, stream>>>(Xb, Wb, bq, bk, bv, Qb, Kb, Vt);
  attn_kernel<<<1024, 256, 0, stream>>>(Qb, Kb, Vt, mask, out);
}